// Round 1
// baseline (134.345 us; speedup 1.0000x reference)
//
#include <hip/hip_runtime.h>

// VQ color lookup: for each pixel (B=8, H=W=256, C=3, layout BCHW) find the
// nearest of K=512 palette colors (squared-L2 argmin), write the quantized
// color back in BCHW, and accumulate loss = 11 * mean((zq - z)^2).
//
// Numerics: the distance is computed EXACTLY like the numpy reference
// (z2 - 2*cross + t2, left-assoc, no fma contraction) so the argmin
// tie-breaking matches bit-for-bit and no near-tie index flips occur.

#define KPAL 512
#define HW   65536            // 256*256
#define CHW  (3 * HW)
#define NPIX (8 * HW)         // 524288 pixels
#define NELEM (NPIX * 3)      // 1572864 output color elements

__global__ __launch_bounds__(256)
void vq_kernel(const float* __restrict__ z,
               const float* __restrict__ table,
               float* __restrict__ out,
               float* __restrict__ loss)
{
    __shared__ float4 tab[KPAL];   // (t0, t1, t2, ||t||^2) per entry — 8 KB
    const int t = threadIdx.x;

    // Stage palette into LDS; precompute ||t||^2 with np-matching rounding.
    for (int k = t; k < KPAL; k += 256) {
        float t0 = table[3 * k + 0];
        float t1 = table[3 * k + 1];
        float t2 = table[3 * k + 2];
        float t2s;
        {
#pragma clang fp contract(off)
            t2s = t0 * t0 + t1 * t1 + t2 * t2;
        }
        tab[k] = make_float4(t0, t1, t2, t2s);
    }
    __syncthreads();

    const int idx  = blockIdx.x * 256 + t;   // pixel id in [0, NPIX)
    const int b    = idx >> 16;              // / 65536
    const int p    = idx & (HW - 1);
    const int base = b * CHW + p;

    const float z0 = z[base];
    const float z1 = z[base + HW];
    const float z2 = z[base + 2 * HW];
    float z2s;
    {
#pragma clang fp contract(off)
        z2s = z0 * z0 + z1 * z1 + z2 * z2;
    }

    float best = 3.4e38f;
    int   bi   = 0;
#pragma unroll 4
    for (int k = 0; k < KPAL; ++k) {
        const float4 c = tab[k];
        float d2;
        {
#pragma clang fp contract(off)
            float cross = z0 * c.x + z1 * c.y + z2 * c.z;   // left-assoc
            d2 = z2s - 2.0f * cross + c.w;                  // (z2s - 2c) + t2
        }
        if (d2 < best) { best = d2; bi = k; }   // strict < keeps first index
    }

    const float4 c = tab[bi];
    out[base]          = c.x;
    out[base + HW]     = c.y;
    out[base + 2 * HW] = c.z;

    // loss partial: sum of squared diffs for this pixel's 3 channels
    const float d0 = c.x - z0, d1 = c.y - z1, d2v = c.z - z2;
    float lsum = d0 * d0 + d1 * d1 + d2v * d2v;

    // wave(64) reduce
    for (int off = 32; off > 0; off >>= 1)
        lsum += __shfl_down(lsum, off);

    __shared__ float wsum[4];
    const int wid = t >> 6;
    if ((t & 63) == 0) wsum[wid] = lsum;
    __syncthreads();
    if (t == 0) {
        const float s = wsum[0] + wsum[1] + wsum[2] + wsum[3];
        atomicAdd(loss, s * (11.0f / (float)NELEM));
    }
}

extern "C" void kernel_launch(void* const* d_in, const int* in_sizes, int n_in,
                              void* d_out, int out_size, void* d_ws, size_t ws_size,
                              hipStream_t stream)
{
    const float* z     = (const float*)d_in[0];
    const float* table = (const float*)d_in[1];
    float* out  = (float*)d_out;
    float* loss = out + NELEM;

    // d_out is poisoned 0xAA before every launch — zero the loss accumulator.
    hipMemsetAsync(loss, 0, sizeof(float), stream);

    vq_kernel<<<NPIX / 256, 256, 0, stream>>>(z, table, out, loss);
}

// Round 3
// 123.363 us; speedup vs baseline: 1.0890x; 1.0890x over previous
//
#include <hip/hip_runtime.h>

// VQ color lookup, round 2 (resubmit — R2 bench was an infra failure).
// R1 was DS-pipe bound (512 ds_read_b128/thread ≈ 82 µs/CU). Fix:
//  - palette goes through SGPRs: uniform-index loads from a float4-packed
//    copy in d_ws -> s_load_dwordx4, zero DS/VMEM-per-lane cost in the loop.
//  - 2 pixels per thread as float2 -> packed fp32 VALU (v_pk_mul/add_f32).
// Distance formula kept bit-identical to numpy ref (contract off, left-assoc):
// R1 passed with absmax 0.0.

#define KPAL 512
#define HW   65536            // 256*256
#define CHW  (3 * HW)
#define NPIX (8 * HW)         // 524288 pixels
#define NELEM (NPIX * 3)      // 1572864 output color elements

typedef float f2 __attribute__((ext_vector_type(2)));

// Pack table[512*3] -> pal[512] = (t0, t1, t2, ||t||^2), 16B aligned.
__global__ __launch_bounds__(256)
void prep_kernel(const float* __restrict__ table, float4* __restrict__ pal)
{
    const int k = blockIdx.x * 256 + threadIdx.x;
    if (k >= KPAL) return;
    const float t0 = table[3 * k + 0];
    const float t1 = table[3 * k + 1];
    const float t2 = table[3 * k + 2];
    float t2s;
    {
#pragma clang fp contract(off)
        t2s = t0 * t0 + t1 * t1 + t2 * t2;
    }
    pal[k] = make_float4(t0, t1, t2, t2s);
}

__global__ __launch_bounds__(256)
void vq_kernel(const float* __restrict__ z,
               const float4* __restrict__ pal,
               float* __restrict__ out,
               float* __restrict__ loss)
{
    const int t    = threadIdx.x;
    const int pair = blockIdx.x * 256 + t;      // pixel-pair id in [0, NPIX/2)
    const int idx  = pair * 2;                  // first pixel of the pair
    const int b    = idx >> 16;                 // / 65536 (pairs never straddle)
    const int p    = idx & (HW - 1);
    const int base = b * CHW + p;

    const f2 z0 = *(const f2*)(z + base);
    const f2 z1 = *(const f2*)(z + base + HW);
    const f2 z2 = *(const f2*)(z + base + 2 * HW);
    f2 z2s;
    {
#pragma clang fp contract(off)
        z2s = z0 * z0 + z1 * z1 + z2 * z2;
    }

    float b0 = 3.4e38f, b1 = 3.4e38f;
    int   i0 = 0,       i1 = 0;
#pragma unroll 4
    for (int k = 0; k < KPAL; ++k) {
        const float4 c = pal[k];                // uniform addr -> s_load
        f2 d2;
        {
#pragma clang fp contract(off)
            f2 cr = z0 * c.x;
            cr = cr + z1 * c.y;
            cr = cr + z2 * c.z;                 // left-assoc, matches np
            d2 = z2s - 2.0f * cr + c.w;         // ((z2s - 2c) + t2)
        }
        if (d2.x < b0) { b0 = d2.x; i0 = k; }   // strict <: first-index ties
        if (d2.y < b1) { b1 = d2.y; i1 = k; }
    }

    const float4 c0 = pal[i0];
    const float4 c1 = pal[i1];
    *(f2*)(out + base)          = (f2){c0.x, c1.x};
    *(f2*)(out + base + HW)     = (f2){c0.y, c1.y};
    *(f2*)(out + base + 2 * HW) = (f2){c0.z, c1.z};

    // loss partials (both pixels, 6 channels)
    const float d00 = c0.x - z0.x, d01 = c0.y - z1.x, d02 = c0.z - z2.x;
    const float d10 = c1.x - z0.y, d11 = c1.y - z1.y, d12 = c1.z - z2.y;
    float lsum = d00 * d00 + d01 * d01 + d02 * d02
               + d10 * d10 + d11 * d11 + d12 * d12;

    for (int off = 32; off > 0; off >>= 1)
        lsum += __shfl_down(lsum, off);

    __shared__ float wsum[4];
    const int wid = t >> 6;
    if ((t & 63) == 0) wsum[wid] = lsum;
    __syncthreads();
    if (t == 0) {
        const float s = wsum[0] + wsum[1] + wsum[2] + wsum[3];
        atomicAdd(loss, s * (11.0f / (float)NELEM));
    }
}

extern "C" void kernel_launch(void* const* d_in, const int* in_sizes, int n_in,
                              void* d_out, int out_size, void* d_ws, size_t ws_size,
                              hipStream_t stream)
{
    const float* z     = (const float*)d_in[0];
    const float* table = (const float*)d_in[1];
    float*  out  = (float*)d_out;
    float*  loss = out + NELEM;
    float4* pal  = (float4*)d_ws;               // 512 * 16 B = 8 KB scratch

    hipMemsetAsync(loss, 0, sizeof(float), stream);
    prep_kernel<<<2, 256, 0, stream>>>(table, pal);
    vq_kernel<<<NPIX / 512, 256, 0, stream>>>(z, pal, out, loss);
}